// Round 2
// baseline (841.560 us; speedup 1.0000x reference)
//
#include <hip/hip_runtime.h>

#define B_    16
#define H_    64
#define W_    64
#define HW_   4096
#define C_    256
#define C4_   64
#define KO_   36
#define HO_   128
#define POUT_ 16384
#define COUT_ 256

// ---------------------------------------------------------------------------
// k0: transpose enc_w [36][64][3][3] -> wt[(ci*9+tap)][36] so that k2 can do
// wave-uniform contiguous scalar loads of all 36 output channels.
// ---------------------------------------------------------------------------
__global__ __launch_bounds__(256) void k0_transpose(const float* __restrict__ enc_w,
                                                    float* __restrict__ wt) {
  int idx = blockIdx.x * 256 + threadIdx.x;
  if (idx >= 576 * 36) return;
  int ko = idx % 36;
  int ct = idx / 36;  // ci*9 + tap
  wt[ct * 36 + ko] = enc_w[ko * 576 + ct];
}

// ---------------------------------------------------------------------------
// k1: down 1x1 conv.  x is (B, HW, C) i.e. NHWC; GEMM M=HW, N=64, K=256.
// Output kt1 in NCHW (B,64,64,64) for k2's spatial staging.
// Block: 64 positions x 64 outputs, 256 threads, 4x4 register tile.
// ---------------------------------------------------------------------------
__global__ __launch_bounds__(256) void k1_down(const float* __restrict__ x,
                                               const float* __restrict__ dw,
                                               const float* __restrict__ db,
                                               float* __restrict__ kt1) {
  int bid = blockIdx.x;
  int b = bid >> 6;
  int p0 = (bid & 63) << 6;
  int tid = threadIdx.x;
  __shared__ float As[16][68];  // [kc][pos], +4 pad -> conflict-free transposed writes
  __shared__ float Bs[16][64];  // [kc][co]
  int tn = tid & 15, tm = tid >> 4;
  float acc[4][4] = {};
  const float* xb = x + ((size_t)b * HW_ + p0) * C_;
  for (int k0 = 0; k0 < C_; k0 += 16) {
    __syncthreads();
    {  // stage A (transpose x chunk): 64 pos x 16 c
      int pos = tid >> 2, q = tid & 3;
      float4 v = *(const float4*)(xb + pos * C_ + k0 + q * 4);
      As[q * 4 + 0][pos] = v.x; As[q * 4 + 1][pos] = v.y;
      As[q * 4 + 2][pos] = v.z; As[q * 4 + 3][pos] = v.w;
    }
    {  // stage B (transpose down_w chunk): 64 co x 16 c
      int co = tid & 63, q = tid >> 6;
      float4 v = *(const float4*)(dw + co * C_ + k0 + q * 4);
      Bs[q * 4 + 0][co] = v.x; Bs[q * 4 + 1][co] = v.y;
      Bs[q * 4 + 2][co] = v.z; Bs[q * 4 + 3][co] = v.w;
    }
    __syncthreads();
#pragma unroll
    for (int kc = 0; kc < 16; kc++) {
      float4 a  = *(const float4*)&As[kc][tm * 4];
      float4 bv = *(const float4*)&Bs[kc][tn * 4];
      float af[4] = {a.x, a.y, a.z, a.w};
      float bf[4] = {bv.x, bv.y, bv.z, bv.w};
#pragma unroll
      for (int i = 0; i < 4; i++)
#pragma unroll
        for (int j = 0; j < 4; j++) acc[i][j] += af[i] * bf[j];
    }
  }
#pragma unroll
  for (int j = 0; j < 4; j++) {
    int co = tn * 4 + j;
    float bias = db[co];
#pragma unroll
    for (int i = 0; i < 4; i++) {
      kt1[((size_t)b * C4_ + co) * HW_ + p0 + tm * 4 + i] = acc[i][j] + bias;
    }
  }
}

// ---------------------------------------------------------------------------
// k2: enc 3x3 conv (64->36, pad 1) + softmax + shuffle-collapse.
// kt[b][pos][k][u] = softmax_k( enc_out[b, k*4+u, h, w] ).
// One thread per position, 36 accumulators; weights read via wave-uniform
// contiguous scalar loads from wt; input staged per-8-channel halo tile in LDS.
// ---------------------------------------------------------------------------
__global__ __launch_bounds__(256) void k2_enc(const float* __restrict__ kt1,
                                              const float* __restrict__ wt,
                                              const float* __restrict__ eb,
                                              float* __restrict__ ktp) {
  int bid = blockIdx.x;
  int b = bid >> 4;
  int t = bid & 15;
  int h0 = (t >> 2) << 4, w0 = (t & 3) << 4;
  int tid = threadIdx.x;
  int lh = tid >> 4, lw = tid & 15;
  __shared__ float xh[8][18][18];
  float e[36];
#pragma unroll
  for (int i = 0; i < 36; i++) e[i] = eb[i];
  const float* kt1b = kt1 + (size_t)b * C4_ * HW_;
  for (int c0 = 0; c0 < C4_; c0 += 8) {
    __syncthreads();
    for (int idx = tid; idx < 8 * 324; idx += 256) {
      int ci = idx / 324;
      int r = idx - ci * 324;
      int hh = r / 18, ww = r - (r / 18) * 18;
      int gh = h0 + hh - 1, gw = w0 + ww - 1;
      float v = 0.f;
      if (gh >= 0 && gh < H_ && gw >= 0 && gw < W_)
        v = kt1b[(size_t)(c0 + ci) * HW_ + gh * W_ + gw];
      xh[ci][hh][ww] = v;
    }
    __syncthreads();
    for (int ci = 0; ci < 8; ci++) {
#pragma unroll
      for (int tap = 0; tap < 9; tap++) {
        int di = tap / 3, dj = tap - (tap / 3) * 3;
        float v = xh[ci][lh + di][lw + dj];
        const float* wr = wt + ((c0 + ci) * 9 + tap) * 36;  // uniform -> s_load
#pragma unroll
        for (int ko = 0; ko < 36; ko++) e[ko] += v * wr[ko];
      }
    }
  }
  // per-u softmax over the 9 taps (in-place in e: e[k*4+u])
#pragma unroll
  for (int u = 0; u < 4; u++) {
    float m = -1e30f;
#pragma unroll
    for (int k = 0; k < 9; k++) m = fmaxf(m, e[k * 4 + u]);
    float s = 0.f;
#pragma unroll
    for (int k = 0; k < 9; k++) {
      float p = __expf(e[k * 4 + u] - m);
      e[k * 4 + u] = p;
      s += p;
    }
    float r = 1.0f / s;
#pragma unroll
    for (int k = 0; k < 9; k++) e[k * 4 + u] *= r;
  }
  int pos = (h0 + lh) * W_ + (w0 + lw);
  float* outp = ktp + ((size_t)b * HW_ + pos) * 36;  // 36 % 4 == 0 -> 16B aligned
#pragma unroll
  for (int k = 0; k < 9; k++) {
    *(float4*)(outp + k * 4) = make_float4(e[k * 4 + 0], e[k * 4 + 1],
                                           e[k * 4 + 2], e[k * 4 + 3]);
  }
}

// ---------------------------------------------------------------------------
// k3: fused CARAFE reassembly + out 1x1 conv.
// Block = (b, h, 16 consecutive w). M-tile = 16 pos x 4 u = 64 output rows,
// N = 256 co, K = 256 c in chunks of 16. A-tile (the reassembled features y)
// is computed on the fly from a 3x18 x-halo and the 16 positions' kt weights.
// 256 threads, 8x8 register tile with split-half fragments.
// ---------------------------------------------------------------------------
__global__ __launch_bounds__(256) void k3_fused(const float* __restrict__ x,
                                                const float* __restrict__ ktp,
                                                const float* __restrict__ ow,
                                                const float* __restrict__ ob,
                                                float* __restrict__ out) {
  int bid = blockIdx.x;
  int w0 = (bid & 3) << 4;
  int h = (bid >> 2) & 63;
  int b = bid >> 8;
  int tid = threadIdx.x;
  int tn = tid & 31, tm = tid >> 5;
  __shared__ float ktt[16][9][4];   // [pos][tap][u]
  __shared__ float xh[54][16];      // [3*18 spatial][16 c]
  __shared__ float As[16][68];      // [kc][m=pos*4+u], +4 pad
  __shared__ float Bs[16][256];     // [kc][co]
  if (tid < 144) {
    float4 v = *(const float4*)(ktp + ((size_t)b * HW_ + h * W_ + w0) * 36 + tid * 4);
    *(float4*)((float*)ktt + tid * 4) = v;
  }
  float acc[8][8] = {};
  const float* xb = x + (size_t)b * HW_ * C_;
  for (int k0 = 0; k0 < C_; k0 += 16) {
    __syncthreads();
    if (tid < 216) {  // stage x halo: 54 spatial x 16 c
      int s = tid >> 2, q = tid & 3;
      int di = s / 18, ww = s - di * 18;
      int gh = h + di - 1, gw = w0 + ww - 1;
      float4 v = make_float4(0.f, 0.f, 0.f, 0.f);
      if (gh >= 0 && gh < H_ && gw >= 0 && gw < W_)
        v = *(const float4*)(xb + ((size_t)gh * W_ + gw) * C_ + k0 + q * 4);
      *(float4*)&xh[s][q * 4] = v;
    }
    {  // stage out_w chunk transposed: Bs[kc][co]
      const float* wr = ow + (size_t)tid * C_ + k0;
      float4 v0 = *(const float4*)(wr + 0);
      float4 v1 = *(const float4*)(wr + 4);
      float4 v2 = *(const float4*)(wr + 8);
      float4 v3 = *(const float4*)(wr + 12);
      Bs[0][tid] = v0.x;  Bs[1][tid] = v0.y;  Bs[2][tid] = v0.z;  Bs[3][tid] = v0.w;
      Bs[4][tid] = v1.x;  Bs[5][tid] = v1.y;  Bs[6][tid] = v1.z;  Bs[7][tid] = v1.w;
      Bs[8][tid] = v2.x;  Bs[9][tid] = v2.y;  Bs[10][tid] = v2.z; Bs[11][tid] = v2.w;
      Bs[12][tid] = v3.x; Bs[13][tid] = v3.y; Bs[14][tid] = v3.z; Bs[15][tid] = v3.w;
    }
    __syncthreads();
    {  // A-tile = reassembled y for this K-chunk: thread (kc, pos) computes 4 u's
      int kc = tid & 15, pos = tid >> 4;
      float a0 = 0.f, a1 = 0.f, a2 = 0.f, a3 = 0.f;
#pragma unroll
      for (int tap = 0; tap < 9; tap++) {
        int di = tap / 3, dj = tap - (tap / 3) * 3;
        float v = xh[di * 18 + pos + dj][kc];
        float4 kv = *(const float4*)&ktt[pos][tap][0];
        a0 += v * kv.x; a1 += v * kv.y; a2 += v * kv.z; a3 += v * kv.w;
      }
      *(float4*)&As[kc][pos * 4] = make_float4(a0, a1, a2, a3);
    }
    __syncthreads();
#pragma unroll
    for (int kc = 0; kc < 16; kc++) {
      float4 va0 = *(const float4*)&As[kc][tm * 4];
      float4 va1 = *(const float4*)&As[kc][(8 + tm) * 4];
      float4 vb0 = *(const float4*)&Bs[kc][tn * 4];
      float4 vb1 = *(const float4*)&Bs[kc][128 + tn * 4];
      float af[8] = {va0.x, va0.y, va0.z, va0.w, va1.x, va1.y, va1.z, va1.w};
      float bf[8] = {vb0.x, vb0.y, vb0.z, vb0.w, vb1.x, vb1.y, vb1.z, vb1.w};
#pragma unroll
      for (int i = 0; i < 8; i++)
#pragma unroll
        for (int j = 0; j < 8; j++) acc[i][j] += af[i] * bf[j];
    }
  }
  float4 ob0 = *(const float4*)(ob + tn * 4);
  float4 ob1 = *(const float4*)(ob + 128 + tn * 4);
  float obf[8] = {ob0.x, ob0.y, ob0.z, ob0.w, ob1.x, ob1.y, ob1.z, ob1.w};
#pragma unroll
  for (int mi = 0; mi < 8; mi++) {
    int m = (mi < 4) ? (tm * 4 + mi) : (32 + tm * 4 + (mi - 4));
    int pos = m >> 2, u = m & 3;
    int w = w0 + pos;
    int i2 = u >> 1, j2 = u & 1;
    int po = (2 * h + i2) * HO_ + 2 * w + j2;
    float* op = out + ((size_t)b * POUT_ + po) * COUT_;
    *(float4*)(op + tn * 4) = make_float4(acc[mi][0] + obf[0], acc[mi][1] + obf[1],
                                          acc[mi][2] + obf[2], acc[mi][3] + obf[3]);
    *(float4*)(op + 128 + tn * 4) = make_float4(acc[mi][4] + obf[4], acc[mi][5] + obf[5],
                                                acc[mi][6] + obf[6], acc[mi][7] + obf[7]);
  }
}

// ---------------------------------------------------------------------------
extern "C" void kernel_launch(void* const* d_in, const int* in_sizes, int n_in,
                              void* d_out, int out_size, void* d_ws, size_t ws_size,
                              hipStream_t stream) {
  const float* x      = (const float*)d_in[0];
  const float* down_w = (const float*)d_in[1];
  const float* down_b = (const float*)d_in[2];
  const float* enc_w  = (const float*)d_in[3];
  const float* enc_b  = (const float*)d_in[4];
  const float* out_w  = (const float*)d_in[5];
  const float* out_b  = (const float*)d_in[6];
  float* out = (float*)d_out;
  float* ws  = (float*)d_ws;

  float* kt1 = ws;                      // B*64*HW           = 4,194,304 floats
  float* ktp = ws + 4194304;            // B*HW*36           = 2,359,296 floats
  float* wt  = ws + 4194304 + 2359296;  // 576*36            =    20,736 floats
  // total ws use: ~26.3 MB

  k0_transpose<<<81, 256, 0, stream>>>(enc_w, wt);
  k1_down<<<B_ * 64, 256, 0, stream>>>(x, down_w, down_b, kt1);
  k2_enc<<<B_ * 16, 256, 0, stream>>>(kt1, wt, enc_b, ktp);
  k3_fused<<<B_ * 64 * 4, 256, 0, stream>>>(x, ktp, out_w, out_b, out);
}

// Round 7
// 519.760 us; speedup vs baseline: 1.6191x; 1.6191x over previous
//
#include <hip/hip_runtime.h>

#define B_    16
#define H_    64
#define W_    64
#define HW_   4096
#define C_    256
#define C4_   64
#define HO_   128
#define POUT_ 16384
#define COUT_ 256

typedef __bf16 bf16x8 __attribute__((ext_vector_type(8)));
typedef __bf16 bf16x4v __attribute__((ext_vector_type(4)));
typedef float f32x4 __attribute__((ext_vector_type(4)));

// ---------------------------------------------------------------------------
// k0: transpose enc_w [36][64][3][3] -> wt[(ci*9+tap)][36] for k2's uniform loads
// ---------------------------------------------------------------------------
__global__ __launch_bounds__(256) void k0_transpose(const float* __restrict__ enc_w,
                                                    float* __restrict__ wt) {
  int idx = blockIdx.x * 256 + threadIdx.x;
  if (idx >= 576 * 36) return;
  int ko = idx % 36;
  int ct = idx / 36;
  wt[ct * 36 + ko] = enc_w[ko * 576 + ct];
}

// ---------------------------------------------------------------------------
// k0b: out_w -> bf16, pre-swizzled per-64-channel-chunk image for k3's Bs tiles.
// Image: chunk ch (c=ch*64..+63), row n=co (128B of bf16 k-contig), byte offset
// within row XOR-swizzled: kb ^ ((row&7)<<4).  owb aliases kt1 (launched after k2).
// ---------------------------------------------------------------------------
__global__ __launch_bounds__(256) void k0b_prep(const float* __restrict__ ow,
                                                unsigned short* __restrict__ owb) {
  int id = blockIdx.x * 256 + threadIdx.x;  // 65536 = 256 co x 256 c
  int co = id >> 8, c = id & 255;
  float v = ow[co * 256 + c];
  union { __bf16 h; unsigned short u; } cv;
  cv.h = (__bf16)v;
  int ch = c >> 6, kl = c & 63;
  int X = ch * 32768 + co * 128 + ((kl * 2) ^ ((co & 7) << 4));
  *(unsigned short*)((unsigned char*)owb + X) = cv.u;
}

// ---------------------------------------------------------------------------
// k1: down 1x1 conv.
// ---------------------------------------------------------------------------
__global__ __launch_bounds__(256) void k1_down(const float* __restrict__ x,
                                               const float* __restrict__ dw,
                                               const float* __restrict__ db,
                                               float* __restrict__ kt1) {
  int bid = blockIdx.x;
  int b = bid >> 6;
  int p0 = (bid & 63) << 6;
  int tid = threadIdx.x;
  __shared__ float As[16][68];
  __shared__ float Bs[16][64];
  int tn = tid & 15, tm = tid >> 4;
  float acc[4][4] = {};
  const float* xb = x + ((size_t)b * HW_ + p0) * C_;
  for (int k0 = 0; k0 < C_; k0 += 16) {
    __syncthreads();
    {
      int pos = tid >> 2, q = tid & 3;
      float4 v = *(const float4*)(xb + pos * C_ + k0 + q * 4);
      As[q * 4 + 0][pos] = v.x; As[q * 4 + 1][pos] = v.y;
      As[q * 4 + 2][pos] = v.z; As[q * 4 + 3][pos] = v.w;
    }
    {
      int co = tid & 63, q = tid >> 6;
      float4 v = *(const float4*)(dw + co * C_ + k0 + q * 4);
      Bs[q * 4 + 0][co] = v.x; Bs[q * 4 + 1][co] = v.y;
      Bs[q * 4 + 2][co] = v.z; Bs[q * 4 + 3][co] = v.w;
    }
    __syncthreads();
#pragma unroll
    for (int kc = 0; kc < 16; kc++) {
      float4 a  = *(const float4*)&As[kc][tm * 4];
      float4 bv = *(const float4*)&Bs[kc][tn * 4];
      float af[4] = {a.x, a.y, a.z, a.w};
      float bfv[4] = {bv.x, bv.y, bv.z, bv.w};
#pragma unroll
      for (int i = 0; i < 4; i++)
#pragma unroll
        for (int j = 0; j < 4; j++) acc[i][j] += af[i] * bfv[j];
    }
  }
#pragma unroll
  for (int j = 0; j < 4; j++) {
    int co = tn * 4 + j;
    float bias = db[co];
#pragma unroll
    for (int i = 0; i < 4; i++) {
      kt1[((size_t)b * C4_ + co) * HW_ + p0 + tm * 4 + i] = acc[i][j] + bias;
    }
  }
}

// ---------------------------------------------------------------------------
// k2: enc 3x3 conv + softmax + shuffle-collapse.
// ---------------------------------------------------------------------------
__global__ __launch_bounds__(256) void k2_enc(const float* __restrict__ kt1,
                                              const float* __restrict__ wt,
                                              const float* __restrict__ eb,
                                              float* __restrict__ ktp) {
  int bid = blockIdx.x;
  int b = bid >> 4;
  int t = bid & 15;
  int h0 = (t >> 2) << 4, w0 = (t & 3) << 4;
  int tid = threadIdx.x;
  int lh = tid >> 4, lw = tid & 15;
  __shared__ float xh[8][18][18];
  float e[36];
#pragma unroll
  for (int i = 0; i < 36; i++) e[i] = eb[i];
  const float* kt1b = kt1 + (size_t)b * C4_ * HW_;
  for (int c0 = 0; c0 < C4_; c0 += 8) {
    __syncthreads();
    for (int idx = tid; idx < 8 * 324; idx += 256) {
      int ci = idx / 324;
      int r = idx - ci * 324;
      int hh = r / 18, ww = r - (r / 18) * 18;
      int gh = h0 + hh - 1, gw = w0 + ww - 1;
      float v = 0.f;
      if (gh >= 0 && gh < H_ && gw >= 0 && gw < W_)
        v = kt1b[(size_t)(c0 + ci) * HW_ + gh * W_ + gw];
      xh[ci][hh][ww] = v;
    }
    __syncthreads();
    for (int ci = 0; ci < 8; ci++) {
#pragma unroll
      for (int tap = 0; tap < 9; tap++) {
        int di = tap / 3, dj = tap - (tap / 3) * 3;
        float v = xh[ci][lh + di][lw + dj];
        const float* wr = wt + ((c0 + ci) * 9 + tap) * 36;
#pragma unroll
        for (int ko = 0; ko < 36; ko++) e[ko] += v * wr[ko];
      }
    }
  }
#pragma unroll
  for (int u = 0; u < 4; u++) {
    float m = -1e30f;
#pragma unroll
    for (int k = 0; k < 9; k++) m = fmaxf(m, e[k * 4 + u]);
    float s = 0.f;
#pragma unroll
    for (int k = 0; k < 9; k++) {
      float p = __expf(e[k * 4 + u] - m);
      e[k * 4 + u] = p;
      s += p;
    }
    float r = 1.0f / s;
#pragma unroll
    for (int k = 0; k < 9; k++) e[k * 4 + u] *= r;
  }
  int pos = (h0 + lh) * W_ + (w0 + lw);
  float* outp = ktp + ((size_t)b * HW_ + pos) * 36;
#pragma unroll
  for (int k = 0; k < 9; k++) {
    *(float4*)(outp + k * 4) = make_float4(e[k * 4 + 0], e[k * 4 + 1],
                                           e[k * 4 + 2], e[k * 4 + 3]);
  }
}

// ---------------------------------------------------------------------------
// k3: fused reassembly + out 1x1 conv via bf16 MFMA (fp32 accumulate).
// Block = (b, h, 16 w).  GEMM: M=64 (16 pos x 4 u), N=256, K=256 in BK=64 chunks.
// A-tile (reassembled y) computed fp32 from x-halo, converted bf16 -> LDS.
// LDS rows are K-contiguous 128B with XOR swizzle (kb ^ (row&7)<<4) on both
// write and read -> conflict-free ds_read_b128 fragments.
// Fragment layout (16x16x32): A row=lane&15, k=(lane>>4)*8+e; B col=lane&15,
// same k; D col=lane&15, row=(lane>>4)*4+reg (m89-verified).
// ---------------------------------------------------------------------------
#define BS_OFF 0
#define AS_OFF 32768
#define XH_OFF 40960
#define KT_OFF 54784

__global__ __launch_bounds__(256) void k3_mfma(const float* __restrict__ x,
                                               const unsigned short* __restrict__ owb,
                                               const float* __restrict__ ktp,
                                               const float* __restrict__ ob,
                                               float* __restrict__ out) {
  int bid = blockIdx.x;
  int w0 = (bid & 3) << 4;
  int h = (bid >> 2) & 63;
  int b = bid >> 8;
  int tid = threadIdx.x;
  int lane = tid & 63, wv = tid >> 6;
  int lr = lane & 15, hi = lane >> 4;
  __shared__ float4 smem16[3568];  // 57088 B
  unsigned char* sb = (unsigned char*)smem16;

  // stage ktt: [pos][tap][u] fp32 (16*9*4 floats)
  if (tid < 144) {
    float4 v = *(const float4*)(ktp + ((size_t)b * HW_ + h * W_ + w0) * 36 + tid * 4);
    *(float4*)(sb + KT_OFF + tid * 16) = v;
  }

  f32x4 acc[4][4];
#pragma unroll
  for (int i = 0; i < 4; i++)
#pragma unroll
    for (int j = 0; j < 4; j++) acc[i][j] = 0.f;

  const float* xb = x + (size_t)b * HW_ * C_;
  int pos_r = tid >> 4, kcg = tid & 15;  // reassembly role
  int s_x = tid >> 2, q_x = tid & 3;     // xh staging role

  for (int ch = 0; ch < 4; ch++) {
    __syncthreads();
    // stage Bs: 32KB pre-swizzled bf16 image, linear 16B/lane (coalesced)
    const unsigned char* bsrc = (const unsigned char*)owb + ch * 32768;
#pragma unroll
    for (int i = 0; i < 8; i++) {
      uint4 v = *(const uint4*)(bsrc + i * 4096 + tid * 16);
      *(uint4*)(sb + BS_OFF + i * 4096 + tid * 16) = v;
    }
    // stage xh fp32 halo [54][64]
    if (tid < 216) {
      int di = s_x / 18, ww = s_x - di * 18;
      int gh = h + di - 1, gw = w0 + ww - 1;
      bool ok = (gh >= 0 && gh < H_ && gw >= 0 && gw < W_);
      const float* src = xb + (size_t)(gh * W_ + gw) * C_ + ch * 64 + q_x * 16;
#pragma unroll
      for (int j = 0; j < 4; j++) {
        float4 v = ok ? *(const float4*)(src + j * 4) : make_float4(0.f, 0.f, 0.f, 0.f);
        *(float4*)(sb + XH_OFF + s_x * 256 + q_x * 64 + j * 16) = v;
      }
    }
    __syncthreads();
    // reassembly: y[m][kc] fp32 -> bf16 -> As (swizzled)
    {
      float a4[4][4] = {};  // [u][q]
#pragma unroll
      for (int tap = 0; tap < 9; tap++) {
        int di = tap / 3, dj = tap - (tap / 3) * 3;
        float4 xv = *(const float4*)(sb + XH_OFF + (di * 18 + pos_r + dj) * 256 + kcg * 16);
        float4 kv = *(const float4*)(sb + KT_OFF + (pos_r * 9 + tap) * 16);
        float xf[4] = {xv.x, xv.y, xv.z, xv.w};
        float kf[4] = {kv.x, kv.y, kv.z, kv.w};
#pragma unroll
        for (int u = 0; u < 4; u++)
#pragma unroll
          for (int q = 0; q < 4; q++) a4[u][q] += kf[u] * xf[q];
      }
#pragma unroll
      for (int u = 0; u < 4; u++) {
        int row = pos_r * 4 + u;
        bf16x4v pv;
        pv[0] = (__bf16)a4[u][0]; pv[1] = (__bf16)a4[u][1];
        pv[2] = (__bf16)a4[u][2]; pv[3] = (__bf16)a4[u][3];
        int bo = AS_OFF + row * 128 + (((kcg >> 1) * 16) ^ ((row & 7) << 4)) + (kcg & 1) * 8;
        *(bf16x4v*)(sb + bo) = pv;
      }
    }
    __syncthreads();
    // MFMA: 2 ksteps x (4 A-frags + 4 B-frags + 16 mfma)
#pragma unroll
    for (int kk = 0; kk < 2; kk++) {
      int kb = kk * 64 + hi * 16;
      bf16x8 af[4], bfr[4];
#pragma unroll
      for (int mi = 0; mi < 4; mi++) {
        int r = mi * 16 + lr;
        af[mi] = *(const bf16x8*)(sb + AS_OFF + r * 128 + (kb ^ ((r & 7) << 4)));
      }
#pragma unroll
      for (int ni = 0; ni < 4; ni++) {
        int r = wv * 64 + ni * 16 + lr;
        bfr[ni] = *(const bf16x8*)(sb + BS_OFF + r * 128 + (kb ^ ((r & 7) << 4)));
      }
#pragma unroll
      for (int mi = 0; mi < 4; mi++)
#pragma unroll
        for (int ni = 0; ni < 4; ni++)
          acc[mi][ni] = __builtin_amdgcn_mfma_f32_16x16x32_bf16(af[mi], bfr[ni],
                                                                acc[mi][ni], 0, 0, 0);
    }
  }
  // epilogue: D row m = mi*16 + hi*4 + rr, col = wv*64 + ni*16 + lr
  float obf[4];
#pragma unroll
  for (int ni = 0; ni < 4; ni++) obf[ni] = ob[wv * 64 + ni * 16 + lr];
#pragma unroll
  for (int mi = 0; mi < 4; mi++) {
#pragma unroll
    for (int rr = 0; rr < 4; rr++) {
      int m = mi * 16 + hi * 4 + rr;
      int pos = m >> 2, u = m & 3;
      int po = (2 * h + (u >> 1)) * HO_ + 2 * (w0 + pos) + (u & 1);
      float* op = out + ((size_t)b * POUT_ + po) * COUT_ + wv * 64 + lr;
#pragma unroll
      for (int ni = 0; ni < 4; ni++) op[ni * 16] = acc[mi][ni][rr] + obf[ni];
    }
  }
}

// ---------------------------------------------------------------------------
extern "C" void kernel_launch(void* const* d_in, const int* in_sizes, int n_in,
                              void* d_out, int out_size, void* d_ws, size_t ws_size,
                              hipStream_t stream) {
  const float* x      = (const float*)d_in[0];
  const float* down_w = (const float*)d_in[1];
  const float* down_b = (const float*)d_in[2];
  const float* enc_w  = (const float*)d_in[3];
  const float* enc_b  = (const float*)d_in[4];
  const float* out_w  = (const float*)d_in[5];
  const float* out_b  = (const float*)d_in[6];
  float* out = (float*)d_out;
  float* ws  = (float*)d_ws;

  float* kt1 = ws;                      // B*64*HW = 4,194,304 floats (dead after k2)
  float* ktp = ws + 4194304;            // B*HW*36 = 2,359,296 floats
  float* wt  = ws + 4194304 + 2359296;  // 576*36  =    20,736 floats
  unsigned short* owb = (unsigned short*)ws;  // 128KB, aliases kt1; written after k2

  k0_transpose<<<81, 256, 0, stream>>>(enc_w, wt);
  k1_down<<<B_ * 64, 256, 0, stream>>>(x, down_w, down_b, kt1);
  k2_enc<<<B_ * 16, 256, 0, stream>>>(kt1, wt, enc_b, ktp);
  k0b_prep<<<256, 256, 0, stream>>>(out_w, owb);
  k3_mfma<<<B_ * 64 * 4, 256, 0, stream>>>(x, owb, ktp, out_b, out);
}